// Round 8
// baseline (88.822 us; speedup 1.0000x reference)
//
#include <hip/hip_runtime.h>

#define CUBIC_A (-0.75f)

typedef float f4nt __attribute__((ext_vector_type(4)));

__device__ __forceinline__ void nt_store4(float4* p, float4 v) {
    f4nt t;
    t.x = v.x; t.y = v.y; t.z = v.z; t.w = v.w;
    __builtin_nontemporal_store(t, (f4nt*)p);
}

__device__ __forceinline__ float4 add3(float4 a, float4 b, float4 c) {
    return make_float4(a.x + b.x + c.x, a.y + b.y + c.y,
                       a.z + b.z + c.z, a.w + b.w + c.w);
}
__device__ __forceinline__ float4 add2(float4 a, float4 b) {
    return make_float4(a.x + b.x, a.y + b.y, a.z + b.z, a.w + b.w);
}

__device__ __forceinline__ float cubic_w(float d) {
    float ad = fabsf(d);
    if (ad <= 1.0f) return ((CUBIC_A + 2.0f) * ad - (CUBIC_A + 3.0f)) * ad * ad + 1.0f;
    if (ad < 2.0f)  return CUBIC_A * (((ad - 5.0f) * ad + 8.0f) * ad - 4.0f);
    return 0.0f;
}

__device__ __forceinline__ float4 bicubic_pe(const float4* __restrict__ wgt,
                                             int px, int out_hw, int d4) {
    const int i = px / out_hw;
    const int j = px % out_hw;
    const float scale = 64.0f / (float)out_hw;
    const float si = ((float)i + 0.5f) * scale - 0.5f;
    const float sj = ((float)j + 0.5f) * scale - 0.5f;
    const int i0 = (int)floorf(si);
    const int j0 = (int)floorf(sj);
    int ih[4], iw[4];
    float wh[4], ww[4];
#pragma unroll
    for (int a = 0; a < 4; ++a) {
        int tp = i0 - 1 + a;
        wh[a] = cubic_w(si - (float)tp);
        ih[a] = min(63, max(0, tp));
        tp = j0 - 1 + a;
        ww[a] = cubic_w(sj - (float)tp);
        iw[a] = min(63, max(0, tp));
    }
    float ax = 0.f, ay = 0.f, az = 0.f, aw = 0.f;
#pragma unroll
    for (int a = 0; a < 4; ++a) {
        float rx = 0.f, ry = 0.f, rz = 0.f, rw = 0.f;
#pragma unroll
        for (int c = 0; c < 4; ++c) {
            const float4 v = wgt[(size_t)(ih[a] * 64 + iw[c]) * 256 + d4];
            rx = fmaf(ww[c], v.x, rx);
            ry = fmaf(ww[c], v.y, ry);
            rz = fmaf(ww[c], v.z, rz);
            rw = fmaf(ww[c], v.w, rw);
        }
        ax = fmaf(wh[a], rx, ax);
        ay = fmaf(wh[a], ry, ay);
        az = fmaf(wh[a], rz, az);
        aw = fmaf(wh[a], rw, aw);
    }
    return make_float4(ax, ay, az, aw);
}

// GRIDS = [(8,32,32),(8,48,48),(4,64,64),(1,64,64)]; dim=1024 (256 float4).
// 256-thread blocks; each block owns ONE (pixel, frame-half) pair:
// frame-half fh handles frames {fh, fh+2, ...} -> serial depth t/2.
// x-loads are issued FIRST (independent) so HBM latency hides under bicubic.
// blocks: [0,2048) g0 | [2048,6656) g1 | [6656,14848) g2 | [14848,18944) g3
// fh is the LOW bit -> both halves of a pixel are dispatch-adjacent (same XCD,
// shared L2 for the duplicated bicubic taps).
__global__ __launch_bounds__(256) void posemb_kernel(
    const float4* __restrict__ x,     // (47104, 256)
    const float4* __restrict__ wgt,   // (4096, 256)
    const float4* __restrict__ tw,    // (16, 256)
    float4* __restrict__ out)         // (47104, 256)
{
    const int b  = blockIdx.x;
    const int d4 = threadIdx.x;

    if (b < 2048) {                            // g0: t=8, 32x32, interp, depth 4
        const int px = b >> 1, fh = b & 1;
        const size_t base = ((size_t)(fh * 1024 + px)) * 256 + d4;
        const size_t st   = (size_t)2048 * 256;        // 2 frames
        const float4 xv0 = x[base];
        const float4 xv1 = x[base + st];
        const float4 xv2 = x[base + 2 * st];
        const float4 xv3 = x[base + 3 * st];
        const float4 tv0 = tw[(size_t)(fh    ) * 256 + d4];
        const float4 tv1 = tw[(size_t)(fh + 2) * 256 + d4];
        const float4 tv2 = tw[(size_t)(fh + 4) * 256 + d4];
        const float4 tv3 = tw[(size_t)(fh + 6) * 256 + d4];
        const float4 pe = bicubic_pe(wgt, px, 32, d4);
        nt_store4(&out[base],          add3(xv0, pe, tv0));
        nt_store4(&out[base + st],     add3(xv1, pe, tv1));
        nt_store4(&out[base + 2 * st], add3(xv2, pe, tv2));
        nt_store4(&out[base + 3 * st], add3(xv3, pe, tv3));
    } else if (b < 6656) {                     // g1: t=8, 48x48, interp, depth 4
        const int r = b - 2048;
        const int px = r >> 1, fh = r & 1;
        const size_t base = ((size_t)(8192 + fh * 2304 + px)) * 256 + d4;
        const size_t st   = (size_t)2 * 2304 * 256;
        const float4 xv0 = x[base];
        const float4 xv1 = x[base + st];
        const float4 xv2 = x[base + 2 * st];
        const float4 xv3 = x[base + 3 * st];
        const float4 tv0 = tw[(size_t)(fh    ) * 256 + d4];
        const float4 tv1 = tw[(size_t)(fh + 2) * 256 + d4];
        const float4 tv2 = tw[(size_t)(fh + 4) * 256 + d4];
        const float4 tv3 = tw[(size_t)(fh + 6) * 256 + d4];
        const float4 pe = bicubic_pe(wgt, px, 48, d4);
        nt_store4(&out[base],          add3(xv0, pe, tv0));
        nt_store4(&out[base + st],     add3(xv1, pe, tv1));
        nt_store4(&out[base + 2 * st], add3(xv2, pe, tv2));
        nt_store4(&out[base + 3 * st], add3(xv3, pe, tv3));
    } else if (b < 14848) {                    // g2: t=4, 64x64, direct, depth 2
        const int r = b - 6656;
        const int px = r >> 1, fh = r & 1;
        const size_t base = ((size_t)(26624 + fh * 4096 + px)) * 256 + d4;
        const size_t st   = (size_t)2 * 4096 * 256;
        const float4 xv0 = x[base];
        const float4 xv1 = x[base + st];
        const float4 pe  = wgt[(size_t)px * 256 + d4];
        const float4 tv0 = tw[(size_t)(fh    ) * 256 + d4];
        const float4 tv1 = tw[(size_t)(fh + 2) * 256 + d4];
        nt_store4(&out[base],      add3(xv0, pe, tv0));
        nt_store4(&out[base + st], add3(xv1, pe, tv1));
    } else {                                   // g3: t=1, 64x64, direct, depth 1
        const int px = b - 14848;
        const size_t e = ((size_t)(43008 + px)) * 256 + d4;
        const float4 xv = x[e];
        const float4 pe = wgt[(size_t)px * 256 + d4];
        nt_store4(&out[e], add2(xv, pe));
    }
}

extern "C" void kernel_launch(void* const* d_in, const int* in_sizes, int n_in,
                              void* d_out, int out_size, void* d_ws, size_t ws_size,
                              hipStream_t stream) {
    const float4* x   = (const float4*)d_in[0];
    const float4* wgt = (const float4*)d_in[1];
    const float4* tw  = (const float4*)d_in[2];
    float4* out = (float4*)d_out;
    // 2048 + 4608 + 8192 + 4096 = 18944 blocks x 256 threads
    posemb_kernel<<<18944, 256, 0, stream>>>(x, wgt, tw, out);
}

// Round 9
// 83.005 us; speedup vs baseline: 1.0701x; 1.0701x over previous
//
#include <hip/hip_runtime.h>

#define CUBIC_A (-0.75f)

typedef float f4nt __attribute__((ext_vector_type(4)));

__device__ __forceinline__ void nt_store4(float4* p, float4 v) {
    f4nt t;
    t.x = v.x; t.y = v.y; t.z = v.z; t.w = v.w;
    __builtin_nontemporal_store(t, (f4nt*)p);
}

__device__ __forceinline__ float4 add3(float4 a, float4 b, float4 c) {
    return make_float4(a.x + b.x + c.x, a.y + b.y + c.y,
                       a.z + b.z + c.z, a.w + b.w + c.w);
}
__device__ __forceinline__ float4 add2(float4 a, float4 b) {
    return make_float4(a.x + b.x, a.y + b.y, a.z + b.z, a.w + b.w);
}

__device__ __forceinline__ float cubic_w(float d) {
    float ad = fabsf(d);
    if (ad <= 1.0f) return ((CUBIC_A + 2.0f) * ad - (CUBIC_A + 3.0f)) * ad * ad + 1.0f;
    if (ad < 2.0f)  return CUBIC_A * (((ad - 5.0f) * ad + 8.0f) * ad - 4.0f);
    return 0.0f;
}

__device__ __forceinline__ float4 bicubic_pe(const float4* __restrict__ wgt,
                                             int px, int out_hw, int d4) {
    const int i = px / out_hw;
    const int j = px % out_hw;
    const float scale = 64.0f / (float)out_hw;
    const float si = ((float)i + 0.5f) * scale - 0.5f;
    const float sj = ((float)j + 0.5f) * scale - 0.5f;
    const int i0 = (int)floorf(si);
    const int j0 = (int)floorf(sj);
    int ih[4], iw[4];
    float wh[4], ww[4];
#pragma unroll
    for (int a = 0; a < 4; ++a) {
        int tp = i0 - 1 + a;
        wh[a] = cubic_w(si - (float)tp);
        ih[a] = min(63, max(0, tp));
        tp = j0 - 1 + a;
        ww[a] = cubic_w(sj - (float)tp);
        iw[a] = min(63, max(0, tp));
    }
    float ax = 0.f, ay = 0.f, az = 0.f, aw = 0.f;
#pragma unroll
    for (int a = 0; a < 4; ++a) {
        float rx = 0.f, ry = 0.f, rz = 0.f, rw = 0.f;
#pragma unroll
        for (int c = 0; c < 4; ++c) {
            const float4 v = wgt[(size_t)(ih[a] * 64 + iw[c]) * 256 + d4];
            rx = fmaf(ww[c], v.x, rx);
            ry = fmaf(ww[c], v.y, ry);
            rz = fmaf(ww[c], v.z, rz);
            rw = fmaf(ww[c], v.w, rw);
        }
        ax = fmaf(wh[a], rx, ax);
        ay = fmaf(wh[a], ry, ay);
        az = fmaf(wh[a], rz, az);
        aw = fmaf(wh[a], rw, aw);
    }
    return make_float4(ax, ay, az, aw);
}

// Kernel A: materialize interpolated pe rows into ws (normal stores -> cache-hot).
// ws rows (float4[256]): [0,1024) = 32x32 pixels, [1024,3328) = 48x48 pixels.
__global__ __launch_bounds__(256) void pe_build_kernel(
    const float4* __restrict__ wgt,   // (4096, 256)
    float4* __restrict__ pe_ws)       // (3328, 256)
{
    const int b  = blockIdx.x;
    const int d4 = threadIdx.x;
    float4 pe;
    if (b < 1024) pe = bicubic_pe(wgt, b, 32, d4);
    else          pe = bicubic_pe(wgt, b - 1024, 48, d4);
    pe_ws[(size_t)b * 256 + d4] = pe;
}

// Kernel B: R7's winning structure (512-thread blocks, one pixel per block,
// fh = tid>>8 handles frames {fh, fh+2, ...} -> serial depth t/2; x-loads
// issued first), but pe comes from the table -> every block is a lean
// stream: <=5 row-loads + <=4 NT row-stores, no FMA chain.
// blocks: [0,1024) g0 | [1024,3328) g1 | [3328,7424) g2 | [7424,9472) g3(2px)
__global__ __launch_bounds__(512) void posemb_add_kernel(
    const float4* __restrict__ x,     // (47104, 256)
    const float4* __restrict__ wgt,   // (4096, 256)
    const float4* __restrict__ tw,    // (16, 256)
    const float4* __restrict__ pe_ws, // (3328, 256)
    float4* __restrict__ out)         // (47104, 256)
{
    const int b   = blockIdx.x;
    const int tid = threadIdx.x;
    const int d4  = tid & 255;
    const int fh  = tid >> 8;   // 0 or 1

    if (b < 1024) {                            // g0: t=8, 32x32, table
        const int px = b;
        const size_t base = ((size_t)(fh * 1024 + px)) * 256 + d4;
        const size_t st   = (size_t)2048 * 256;
        const float4 xv0 = x[base];
        const float4 xv1 = x[base + st];
        const float4 xv2 = x[base + 2 * st];
        const float4 xv3 = x[base + 3 * st];
        const float4 pe  = pe_ws[(size_t)px * 256 + d4];
        const float4 tv0 = tw[(size_t)(fh    ) * 256 + d4];
        const float4 tv1 = tw[(size_t)(fh + 2) * 256 + d4];
        const float4 tv2 = tw[(size_t)(fh + 4) * 256 + d4];
        const float4 tv3 = tw[(size_t)(fh + 6) * 256 + d4];
        nt_store4(&out[base],          add3(xv0, pe, tv0));
        nt_store4(&out[base + st],     add3(xv1, pe, tv1));
        nt_store4(&out[base + 2 * st], add3(xv2, pe, tv2));
        nt_store4(&out[base + 3 * st], add3(xv3, pe, tv3));
    } else if (b < 3328) {                     // g1: t=8, 48x48, table
        const int px = b - 1024;
        const size_t base = ((size_t)(8192 + fh * 2304 + px)) * 256 + d4;
        const size_t st   = (size_t)2 * 2304 * 256;
        const float4 xv0 = x[base];
        const float4 xv1 = x[base + st];
        const float4 xv2 = x[base + 2 * st];
        const float4 xv3 = x[base + 3 * st];
        const float4 pe  = pe_ws[(size_t)(1024 + px) * 256 + d4];
        const float4 tv0 = tw[(size_t)(fh    ) * 256 + d4];
        const float4 tv1 = tw[(size_t)(fh + 2) * 256 + d4];
        const float4 tv2 = tw[(size_t)(fh + 4) * 256 + d4];
        const float4 tv3 = tw[(size_t)(fh + 6) * 256 + d4];
        nt_store4(&out[base],          add3(xv0, pe, tv0));
        nt_store4(&out[base + st],     add3(xv1, pe, tv1));
        nt_store4(&out[base + 2 * st], add3(xv2, pe, tv2));
        nt_store4(&out[base + 3 * st], add3(xv3, pe, tv3));
    } else if (b < 7424) {                     // g2: t=4, 64x64, direct weight
        const int px = b - 3328;
        const size_t base = ((size_t)(26624 + fh * 4096 + px)) * 256 + d4;
        const size_t st   = (size_t)2 * 4096 * 256;
        const float4 xv0 = x[base];
        const float4 xv1 = x[base + st];
        const float4 pe  = wgt[(size_t)px * 256 + d4];
        const float4 tv0 = tw[(size_t)(fh    ) * 256 + d4];
        const float4 tv1 = tw[(size_t)(fh + 2) * 256 + d4];
        nt_store4(&out[base],      add3(xv0, pe, tv0));
        nt_store4(&out[base + st], add3(xv1, pe, tv1));
    } else {                                   // g3: t=1, 64x64, direct; 2 px/block
        const int px = 2 * (b - 7424) + fh;
        const size_t e = ((size_t)(43008 + px)) * 256 + d4;
        const float4 xv = x[e];
        const float4 pe = wgt[(size_t)px * 256 + d4];
        nt_store4(&out[e], add2(xv, pe));
    }
}

// Fallback (R7 single-kernel, bicubic inline) if ws is too small.
__global__ __launch_bounds__(512) void posemb_fallback_kernel(
    const float4* __restrict__ x, const float4* __restrict__ wgt,
    const float4* __restrict__ tw, float4* __restrict__ out)
{
    const int b   = blockIdx.x;
    const int tid = threadIdx.x;
    const int d4  = tid & 255;
    const int fh  = tid >> 8;

    if (b < 1024) {
        const int px = b;
        const size_t base = ((size_t)(fh * 1024 + px)) * 256 + d4;
        const size_t st   = (size_t)2048 * 256;
        const float4 xv0 = x[base];
        const float4 xv1 = x[base + st];
        const float4 xv2 = x[base + 2 * st];
        const float4 xv3 = x[base + 3 * st];
        const float4 tv0 = tw[(size_t)(fh    ) * 256 + d4];
        const float4 tv1 = tw[(size_t)(fh + 2) * 256 + d4];
        const float4 tv2 = tw[(size_t)(fh + 4) * 256 + d4];
        const float4 tv3 = tw[(size_t)(fh + 6) * 256 + d4];
        const float4 pe = bicubic_pe(wgt, px, 32, d4);
        nt_store4(&out[base],          add3(xv0, pe, tv0));
        nt_store4(&out[base + st],     add3(xv1, pe, tv1));
        nt_store4(&out[base + 2 * st], add3(xv2, pe, tv2));
        nt_store4(&out[base + 3 * st], add3(xv3, pe, tv3));
    } else if (b < 3328) {
        const int px = b - 1024;
        const size_t base = ((size_t)(8192 + fh * 2304 + px)) * 256 + d4;
        const size_t st   = (size_t)2 * 2304 * 256;
        const float4 xv0 = x[base];
        const float4 xv1 = x[base + st];
        const float4 xv2 = x[base + 2 * st];
        const float4 xv3 = x[base + 3 * st];
        const float4 tv0 = tw[(size_t)(fh    ) * 256 + d4];
        const float4 tv1 = tw[(size_t)(fh + 2) * 256 + d4];
        const float4 tv2 = tw[(size_t)(fh + 4) * 256 + d4];
        const float4 tv3 = tw[(size_t)(fh + 6) * 256 + d4];
        const float4 pe = bicubic_pe(wgt, px, 48, d4);
        nt_store4(&out[base],          add3(xv0, pe, tv0));
        nt_store4(&out[base + st],     add3(xv1, pe, tv1));
        nt_store4(&out[base + 2 * st], add3(xv2, pe, tv2));
        nt_store4(&out[base + 3 * st], add3(xv3, pe, tv3));
    } else if (b < 7424) {
        const int px = b - 3328;
        const size_t base = ((size_t)(26624 + fh * 4096 + px)) * 256 + d4;
        const size_t st   = (size_t)2 * 4096 * 256;
        const float4 xv0 = x[base];
        const float4 xv1 = x[base + st];
        const float4 pe  = wgt[(size_t)px * 256 + d4];
        const float4 tv0 = tw[(size_t)(fh    ) * 256 + d4];
        const float4 tv1 = tw[(size_t)(fh + 2) * 256 + d4];
        nt_store4(&out[base],      add3(xv0, pe, tv0));
        nt_store4(&out[base + st], add3(xv1, pe, tv1));
    } else {
        const int px = 2 * (b - 7424) + fh;
        const size_t e = ((size_t)(43008 + px)) * 256 + d4;
        const float4 xv = x[e];
        const float4 pe = wgt[(size_t)px * 256 + d4];
        nt_store4(&out[e], add2(xv, pe));
    }
}

extern "C" void kernel_launch(void* const* d_in, const int* in_sizes, int n_in,
                              void* d_out, int out_size, void* d_ws, size_t ws_size,
                              hipStream_t stream) {
    const float4* x   = (const float4*)d_in[0];
    const float4* wgt = (const float4*)d_in[1];
    const float4* tw  = (const float4*)d_in[2];
    float4* out = (float4*)d_out;

    const size_t pe_bytes = (size_t)3328 * 256 * sizeof(float4);  // 3.4 MB
    if (ws_size >= pe_bytes) {
        float4* pe_ws = (float4*)d_ws;
        pe_build_kernel<<<3328, 256, 0, stream>>>(wgt, pe_ws);
        posemb_add_kernel<<<9472, 512, 0, stream>>>(x, wgt, tw, pe_ws, out);
    } else {
        posemb_fallback_kernel<<<9472, 512, 0, stream>>>(x, wgt, tw, out);
    }
}

// Round 10
// 77.243 us; speedup vs baseline: 1.1499x; 1.0746x over previous
//
#include <hip/hip_runtime.h>

#define CUBIC_A (-0.75f)

typedef float f4nt __attribute__((ext_vector_type(4)));

__device__ __forceinline__ void nt_store4(float4* p, float4 v) {
    f4nt t;
    t.x = v.x; t.y = v.y; t.z = v.z; t.w = v.w;
    __builtin_nontemporal_store(t, (f4nt*)p);
}

__device__ __forceinline__ float4 add3(float4 a, float4 b, float4 c) {
    return make_float4(a.x + b.x + c.x, a.y + b.y + c.y,
                       a.z + b.z + c.z, a.w + b.w + c.w);
}
__device__ __forceinline__ float4 add2(float4 a, float4 b) {
    return make_float4(a.x + b.x, a.y + b.y, a.z + b.z, a.w + b.w);
}

__device__ __forceinline__ float cubic_w(float d) {
    float ad = fabsf(d);
    if (ad <= 1.0f) return ((CUBIC_A + 2.0f) * ad - (CUBIC_A + 3.0f)) * ad * ad + 1.0f;
    if (ad < 2.0f)  return CUBIC_A * (((ad - 5.0f) * ad + 8.0f) * ad - 4.0f);
    return 0.0f;
}

__device__ __forceinline__ float4 bicubic_pe(const float4* __restrict__ wgt,
                                             int px, int out_hw, int d4) {
    const int i = px / out_hw;
    const int j = px % out_hw;
    const float scale = 64.0f / (float)out_hw;
    const float si = ((float)i + 0.5f) * scale - 0.5f;
    const float sj = ((float)j + 0.5f) * scale - 0.5f;
    const int i0 = (int)floorf(si);
    const int j0 = (int)floorf(sj);
    int ih[4], iw[4];
    float wh[4], ww[4];
#pragma unroll
    for (int a = 0; a < 4; ++a) {
        int tp = i0 - 1 + a;
        wh[a] = cubic_w(si - (float)tp);
        ih[a] = min(63, max(0, tp));
        tp = j0 - 1 + a;
        ww[a] = cubic_w(sj - (float)tp);
        iw[a] = min(63, max(0, tp));
    }
    float ax = 0.f, ay = 0.f, az = 0.f, aw = 0.f;
#pragma unroll
    for (int a = 0; a < 4; ++a) {
        float rx = 0.f, ry = 0.f, rz = 0.f, rw = 0.f;
#pragma unroll
        for (int c = 0; c < 4; ++c) {
            const float4 v = wgt[(size_t)(ih[a] * 64 + iw[c]) * 256 + d4];
            rx = fmaf(ww[c], v.x, rx);
            ry = fmaf(ww[c], v.y, ry);
            rz = fmaf(ww[c], v.z, rz);
            rw = fmaf(ww[c], v.w, rw);
        }
        ax = fmaf(wh[a], rx, ax);
        ay = fmaf(wh[a], ry, ay);
        az = fmaf(wh[a], rz, az);
        aw = fmaf(wh[a], rw, aw);
    }
    return make_float4(ax, ay, az, aw);
}

// GRIDS = [(8,32,32),(8,48,48),(4,64,64),(1,64,64)]; dim=1024 (256 float4).
// One 256-thread block per pixel, FULL frame depth per thread (8 KB streamed
// per wave for t=8). __launch_bounds__(256,2) lifts the VGPR cap to ~256 so
// the compiler can keep all 8 x-loads + 8 tw-loads in flight; bicubic taps
// (L2-hot) compute under that latency. NT stores keep out off the L3.
// blocks: [0,1024) g0 | [1024,3328) g1 | [3328,7424) g2 | [7424,9472) g3(2px)
__global__ __launch_bounds__(256, 2) void posemb_kernel(
    const float4* __restrict__ x,     // (47104, 256)
    const float4* __restrict__ wgt,   // (4096, 256)
    const float4* __restrict__ tw,    // (16, 256)
    float4* __restrict__ out)         // (47104, 256)
{
    const int b  = blockIdx.x;
    const int d4 = threadIdx.x;

    if (b < 1024) {                            // g0: t=8, 32x32, interp
        const int px = b;
        const size_t base = (size_t)px * 256 + d4;
        const size_t st   = (size_t)1024 * 256;          // frame stride
        const float4 xv0 = x[base];
        const float4 xv1 = x[base + st];
        const float4 xv2 = x[base + 2 * st];
        const float4 xv3 = x[base + 3 * st];
        const float4 xv4 = x[base + 4 * st];
        const float4 xv5 = x[base + 5 * st];
        const float4 xv6 = x[base + 6 * st];
        const float4 xv7 = x[base + 7 * st];
        const float4 tv0 = tw[(size_t)0 * 256 + d4];
        const float4 tv1 = tw[(size_t)1 * 256 + d4];
        const float4 tv2 = tw[(size_t)2 * 256 + d4];
        const float4 tv3 = tw[(size_t)3 * 256 + d4];
        const float4 tv4 = tw[(size_t)4 * 256 + d4];
        const float4 tv5 = tw[(size_t)5 * 256 + d4];
        const float4 tv6 = tw[(size_t)6 * 256 + d4];
        const float4 tv7 = tw[(size_t)7 * 256 + d4];
        const float4 pe = bicubic_pe(wgt, px, 32, d4);
        nt_store4(&out[base],          add3(xv0, pe, tv0));
        nt_store4(&out[base + st],     add3(xv1, pe, tv1));
        nt_store4(&out[base + 2 * st], add3(xv2, pe, tv2));
        nt_store4(&out[base + 3 * st], add3(xv3, pe, tv3));
        nt_store4(&out[base + 4 * st], add3(xv4, pe, tv4));
        nt_store4(&out[base + 5 * st], add3(xv5, pe, tv5));
        nt_store4(&out[base + 6 * st], add3(xv6, pe, tv6));
        nt_store4(&out[base + 7 * st], add3(xv7, pe, tv7));
    } else if (b < 3328) {                     // g1: t=8, 48x48, interp
        const int px = b - 1024;
        const size_t base = (size_t)(8192 + px) * 256 + d4;
        const size_t st   = (size_t)2304 * 256;
        const float4 xv0 = x[base];
        const float4 xv1 = x[base + st];
        const float4 xv2 = x[base + 2 * st];
        const float4 xv3 = x[base + 3 * st];
        const float4 xv4 = x[base + 4 * st];
        const float4 xv5 = x[base + 5 * st];
        const float4 xv6 = x[base + 6 * st];
        const float4 xv7 = x[base + 7 * st];
        const float4 tv0 = tw[(size_t)0 * 256 + d4];
        const float4 tv1 = tw[(size_t)1 * 256 + d4];
        const float4 tv2 = tw[(size_t)2 * 256 + d4];
        const float4 tv3 = tw[(size_t)3 * 256 + d4];
        const float4 tv4 = tw[(size_t)4 * 256 + d4];
        const float4 tv5 = tw[(size_t)5 * 256 + d4];
        const float4 tv6 = tw[(size_t)6 * 256 + d4];
        const float4 tv7 = tw[(size_t)7 * 256 + d4];
        const float4 pe = bicubic_pe(wgt, px, 48, d4);
        nt_store4(&out[base],          add3(xv0, pe, tv0));
        nt_store4(&out[base + st],     add3(xv1, pe, tv1));
        nt_store4(&out[base + 2 * st], add3(xv2, pe, tv2));
        nt_store4(&out[base + 3 * st], add3(xv3, pe, tv3));
        nt_store4(&out[base + 4 * st], add3(xv4, pe, tv4));
        nt_store4(&out[base + 5 * st], add3(xv5, pe, tv5));
        nt_store4(&out[base + 6 * st], add3(xv6, pe, tv6));
        nt_store4(&out[base + 7 * st], add3(xv7, pe, tv7));
    } else if (b < 7424) {                     // g2: t=4, 64x64, direct
        const int px = b - 3328;
        const size_t base = (size_t)(26624 + px) * 256 + d4;
        const size_t st   = (size_t)4096 * 256;
        const float4 xv0 = x[base];
        const float4 xv1 = x[base + st];
        const float4 xv2 = x[base + 2 * st];
        const float4 xv3 = x[base + 3 * st];
        const float4 tv0 = tw[(size_t)0 * 256 + d4];
        const float4 tv1 = tw[(size_t)1 * 256 + d4];
        const float4 tv2 = tw[(size_t)2 * 256 + d4];
        const float4 tv3 = tw[(size_t)3 * 256 + d4];
        const float4 pe  = wgt[(size_t)px * 256 + d4];
        nt_store4(&out[base],          add3(xv0, pe, tv0));
        nt_store4(&out[base + st],     add3(xv1, pe, tv1));
        nt_store4(&out[base + 2 * st], add3(xv2, pe, tv2));
        nt_store4(&out[base + 3 * st], add3(xv3, pe, tv3));
    } else {                                   // g3: t=1, 64x64, direct; 2 px/block
        const int px0 = 2 * (b - 7424);
        const size_t e0 = (size_t)(43008 + px0) * 256 + d4;
        const size_t e1 = e0 + 256;
        const float4 xv0 = x[e0];
        const float4 xv1 = x[e1];
        const float4 pe0 = wgt[(size_t)px0 * 256 + d4];
        const float4 pe1 = wgt[(size_t)(px0 + 1) * 256 + d4];
        nt_store4(&out[e0], add2(xv0, pe0));
        nt_store4(&out[e1], add2(xv1, pe1));
    }
}

extern "C" void kernel_launch(void* const* d_in, const int* in_sizes, int n_in,
                              void* d_out, int out_size, void* d_ws, size_t ws_size,
                              hipStream_t stream) {
    const float4* x   = (const float4*)d_in[0];
    const float4* wgt = (const float4*)d_in[1];
    const float4* tw  = (const float4*)d_in[2];
    float4* out = (float4*)d_out;
    // 1024 + 2304 + 4096 + 2048 = 9472 blocks x 256 threads
    posemb_kernel<<<9472, 256, 0, stream>>>(x, wgt, tw, out);
}